// Round 5
// baseline (495.478 us; speedup 1.0000x reference)
//
#include <hip/hip_runtime.h>
#include <hip/hip_bf16.h>

#define NB 2
#define NL 2048
#define NH 12
#define ND 64
#define NEWTON 6
#define WV 8            // waves per block
#define TPW 16          // key-tiles per wave = 128/WV

typedef __bf16 bf16x8 __attribute__((ext_vector_type(8)));
typedef __bf16 bf16x4 __attribute__((ext_vector_type(4)));
typedef float f32x4 __attribute__((ext_vector_type(4)));

// DPP row_ror reductions: operate within each 16-lane DPP row (== our quad).
#define ROR_ADD(v, n)                                                         \
  (v) += __int_as_float(__builtin_amdgcn_update_dpp(                          \
      0, __float_as_int(v), 0x120 + (n), 0xF, 0xF, true))
#define ROR_MAX(v, n)                                                         \
  (v) = fmaxf((v), __int_as_float(__builtin_amdgcn_update_dpp(                \
                  0, __float_as_int(v), 0x120 + (n), 0xF, 0xF, true)))

__device__ __forceinline__ void split_bf16(float f, __bf16& hi, __bf16& lo) {
  __bf16 h = (__bf16)f;
  hi = h;
  lo = (__bf16)(f - (float)h);
}

// ---- prep: K -> Khi/Klo [B,H,L,D] planes; V -> Vt_hi/Vt_lo [B,H,D,L] planes ----
__global__ void prep(const float* __restrict__ k, const float* __restrict__ v,
                     __bf16* __restrict__ khi, __bf16* __restrict__ klo,
                     __bf16* __restrict__ vt_hi, __bf16* __restrict__ vt_lo) {
  __shared__ float tile[64][65];
  const int blk = blockIdx.x;
  const int kt = blk & 31;
  const int h = (blk >> 5) % NH;
  const int b = blk / (32 * NH);
  const int t = threadIdx.x;
  const int sub = t >> 4;
  const int c4 = (t & 15) * 4;
  // --- K restride + split (no transpose) ---
#pragma unroll
  for (int rr = 0; rr < 4; ++rr) {
    int key = kt * 64 + rr * 16 + sub;
    int ioff = ((b * NL + key) * NH + h) * ND + c4;
    int ooff = ((b * NH + h) * NL + key) * ND + c4;
    f32x4 val = *(const f32x4*)(k + ioff);
    bf16x4 hv, lv;
#pragma unroll
    for (int i = 0; i < 4; ++i) {
      __bf16 hb, lb;
      split_bf16(val[i], hb, lb);
      hv[i] = hb;
      lv[i] = lb;
    }
    *(bf16x4*)(khi + ooff) = hv;
    *(bf16x4*)(klo + ooff) = lv;
  }
  // --- V transpose + split ---
#pragma unroll
  for (int rr = 0; rr < 4; ++rr) {
    int key = rr * 16 + sub;
    int off = ((b * NL + kt * 64 + key) * NH + h) * ND + c4;
    f32x4 val = *(const f32x4*)(v + off);
    tile[c4 + 0][key] = val[0];
    tile[c4 + 1][key] = val[1];
    tile[c4 + 2][key] = val[2];
    tile[c4 + 3][key] = val[3];
  }
  __syncthreads();
#pragma unroll
  for (int rr = 0; rr < 4; ++rr) {
    int d = rr * 16 + sub;
    int off = ((b * NH + h) * ND + d) * NL + kt * 64 + c4;
    bf16x4 hv, lv;
#pragma unroll
    for (int i = 0; i < 4; ++i) {
      __bf16 hb, lb;
      split_bf16(tile[d][c4 + i], hb, lb);
      hv[i] = hb;
      lv[i] = lb;
    }
    *(bf16x4*)(vt_hi + off) = hv;
    *(bf16x4*)(vt_lo + off) = lv;
  }
}

// ---------------- main fused attention-poly kernel ----------------
// Block = 512 threads = 8 waves, one 16-query tile of one (b,h).
// Wave w owns key-tiles {w + 8t}; scores in registers, MFMA C-layout:
// sc[t][r] = S[row = quad*4+r][key = (w+8t)*16 + l16].
// Newton state cr[r] = c for row quad*4+r, redundant across l16 lanes & waves.
__launch_bounds__(512, 4)
__global__ void attn_poly(const float* __restrict__ qg,
                          const __bf16* __restrict__ khig,
                          const __bf16* __restrict__ klog,
                          const __bf16* __restrict__ vtg_hi,
                          const __bf16* __restrict__ vtg_lo,
                          float* __restrict__ outg) {
  __shared__ __align__(16) float ex[WV][16][68];  // phase5 slabs + phase6 partials
  __shared__ float redmax[WV][16];
  __shared__ float2 redq[2][WV][16];              // (Sum y^-2, Sum y^-3) partials

  const int tid = threadIdx.x;
  const int w = tid >> 6;
  const int lane = tid & 63;
  const int quad = lane >> 4;
  const int l16 = lane & 15;

  const int blk = blockIdx.x;
  const int qt = blk & 127;        // qt inner: 128 consecutive blocks share (b,h)
  const int bh = blk >> 7;
  const int h = bh % NH;
  const int b = bh / NH;
  const int qbase = qt * 16;

  // ---- Q fragments: fp32 * 0.125 -> bf16 hi/lo (A: m=l16, k=quad*8+j) ----
  bf16x8 qhi0, qlo0, qhi1, qlo1;
  {
    const float* qp = qg + ((b * NL + qbase + l16) * NH + h) * ND + quad * 8;
    f32x4 a0 = *(const f32x4*)(qp);
    f32x4 a1 = *(const f32x4*)(qp + 4);
    f32x4 a2 = *(const f32x4*)(qp + 32);
    f32x4 a3 = *(const f32x4*)(qp + 36);
#pragma unroll
    for (int j = 0; j < 4; ++j) {
      __bf16 hb, lb;
      split_bf16(a0[j] * 0.125f, hb, lb); qhi0[j] = hb;     qlo0[j] = lb;
      split_bf16(a1[j] * 0.125f, hb, lb); qhi0[4 + j] = hb; qlo0[4 + j] = lb;
      split_bf16(a2[j] * 0.125f, hb, lb); qhi1[j] = hb;     qlo1[j] = lb;
      split_bf16(a3[j] * 0.125f, hb, lb); qhi1[4 + j] = hb; qlo1[4 + j] = lb;
    }
  }

  // ---- phase 1: S = (Q/8) Kt via hi/lo-split MFMA (lo*lo dropped) ----
  float sc[TPW][4];
  {
    const __bf16* kbh = khig + (size_t)(b * NH + h) * NL * ND;
    const __bf16* kbl = klog + (size_t)(b * NH + h) * NL * ND;
#pragma unroll
    for (int t = 0; t < TPW; ++t) {
      int key = (w + WV * t) * 16 + l16;
      const __bf16* kph = kbh + key * ND + quad * 8;
      const __bf16* kpl = kbl + key * ND + quad * 8;
      bf16x8 khi0 = *(const bf16x8*)kph;
      bf16x8 khi1 = *(const bf16x8*)(kph + 32);
      bf16x8 klo0 = *(const bf16x8*)kpl;
      bf16x8 klo1 = *(const bf16x8*)(kpl + 32);
      f32x4 acc = {0.f, 0.f, 0.f, 0.f};
      acc = __builtin_amdgcn_mfma_f32_16x16x32_bf16(qhi0, khi0, acc, 0, 0, 0);
      acc = __builtin_amdgcn_mfma_f32_16x16x32_bf16(qhi1, khi1, acc, 0, 0, 0);
      acc = __builtin_amdgcn_mfma_f32_16x16x32_bf16(qhi0, klo0, acc, 0, 0, 0);
      acc = __builtin_amdgcn_mfma_f32_16x16x32_bf16(qhi1, klo1, acc, 0, 0, 0);
      acc = __builtin_amdgcn_mfma_f32_16x16x32_bf16(qlo0, khi0, acc, 0, 0, 0);
      acc = __builtin_amdgcn_mfma_f32_16x16x32_bf16(qlo1, khi1, acc, 0, 0, 0);
#pragma unroll
      for (int r = 0; r < 4; ++r) sc[t][r] = acc[r];
    }
  }

  // ---- phase 2: row max (DPP ror tree) -> cr0[r] = -max(row quad*4+r) - 1 ----
  float cr[4];
  {
    float mx[4];
#pragma unroll
    for (int r = 0; r < 4; ++r) {
      float m = sc[0][r];
#pragma unroll
      for (int t = 1; t < TPW; ++t) m = fmaxf(m, sc[t][r]);
      ROR_MAX(m, 8); ROR_MAX(m, 4); ROR_MAX(m, 2); ROR_MAX(m, 1);
      mx[r] = m;
    }
    if (l16 < 4) {
      float v = (l16 == 0) ? mx[0] : (l16 == 1) ? mx[1] : (l16 == 2) ? mx[2] : mx[3];
      redmax[w][quad * 4 + l16] = v;
    }
    __syncthreads();
#pragma unroll
    for (int r = 0; r < 4; ++r) {
      float m = redmax[0][quad * 4 + r];
#pragma unroll
      for (int i = 1; i < WV; ++i) m = fmaxf(m, redmax[i][quad * 4 + r]);
      cr[r] = -m - 1.0f;
    }
  }

  // ---- phase 3: Newton x6, one barrier/iter, DPP trees, no shuffles ----
  for (int it = 0; it < NEWTON; ++it) {
    const int par = it & 1;
    float ps[4] = {0.f, 0.f, 0.f, 0.f};
    float psd[4] = {0.f, 0.f, 0.f, 0.f};
#pragma unroll
    for (int t = 0; t < TPW; ++t) {
#pragma unroll
      for (int r = 0; r < 4; ++r) {
        float y = -(sc[t][r] + cr[r]);          // y >= 1 along the Newton path
        float r1 = __builtin_amdgcn_rcpf(y);
        float r2 = r1 * r1;
        ps[r] += r2;
        psd[r] = fmaf(r2, r1, psd[r]);
      }
    }
#pragma unroll
    for (int r = 0; r < 4; ++r) {
      ROR_ADD(ps[r], 8);  ROR_ADD(ps[r], 4);  ROR_ADD(ps[r], 2);  ROR_ADD(ps[r], 1);
      ROR_ADD(psd[r], 8); ROR_ADD(psd[r], 4); ROR_ADD(psd[r], 2); ROR_ADD(psd[r], 1);
    }
    if (l16 < 4) {
      float a = (l16 == 0) ? ps[0] : (l16 == 1) ? ps[1] : (l16 == 2) ? ps[2] : ps[3];
      float d = (l16 == 0) ? psd[0] : (l16 == 1) ? psd[1] : (l16 == 2) ? psd[2] : psd[3];
      redq[par][w][quad * 4 + l16] = make_float2(a, d);
    }
    __syncthreads();
#pragma unroll
    for (int r = 0; r < 4; ++r) {
      float pst = 0.f, psdt = 0.f;
#pragma unroll
      for (int i = 0; i < WV; ++i) {
        float2 p = redq[par][i][quad * 4 + r];
        pst += p.x;
        psdt += p.y;
      }
      cr[r] -= (pst - 1.0f) * __builtin_amdgcn_rcpf(2.0f * psdt + 1e-8f);
    }
  }

  // ---- phase 4: weights = 1/y^2 (overwrite sc) ----
#pragma unroll
  for (int t = 0; t < TPW; ++t) {
#pragma unroll
    for (int r = 0; r < 4; ++r) {
      float y = -(sc[t][r] + cr[r]);
      float r1 = __builtin_amdgcn_rcpf(y);
      sc[t][r] = r1 * r1;
    }
  }

  // ---- phase 5: O_partial = W * (Vhi + Vlo); W plain bf16; wave-private slab ----
  f32x4 oacc[4];
#pragma unroll
  for (int n = 0; n < 4; ++n) oacc[n] = (f32x4){0.f, 0.f, 0.f, 0.f};
  float* myslab = &ex[w][0][0];                   // 16 rows x 68 stride
  const __bf16* vtb_hi = vtg_hi + (size_t)(b * NH + h) * ND * NL;
  const __bf16* vtb_lo = vtg_lo + (size_t)(b * NH + h) * ND * NL;
#pragma unroll
  for (int p = 0; p < 8; ++p) {
    const int kt0 = w + WV * (2 * p);
    const int kt1 = w + WV * (2 * p + 1);
#pragma unroll
    for (int ts = 0; ts < 2; ++ts) {
      const int t = 2 * p + ts;
#pragma unroll
      for (int r = 0; r < 4; ++r)
        myslab[(quad * 4 + r) * 68 + ts * 16 + l16] = sc[t][r];
    }
    asm volatile("s_waitcnt lgkmcnt(0)" ::: "memory");  // wave-internal exchange
    float wv8[8];
    *(f32x4*)(&wv8[0]) = *(const f32x4*)(myslab + l16 * 68 + quad * 8);
    *(f32x4*)(&wv8[4]) = *(const f32x4*)(myslab + l16 * 68 + quad * 8 + 4);
    bf16x8 aw;
#pragma unroll
    for (int j = 0; j < 8; ++j) aw[j] = (__bf16)wv8[j];
    const int keystart = (quad < 2) ? (kt0 * 16 + quad * 8)
                                    : (kt1 * 16 + (quad - 2) * 8);
#pragma unroll
    for (int n = 0; n < 4; ++n) {
      const __bf16* bph = vtb_hi + (n * 16 + l16) * NL + keystart;
      const __bf16* bpl = vtb_lo + (n * 16 + l16) * NL + keystart;
      bf16x8 bhv = *(const bf16x8*)bph;
      bf16x8 blv = *(const bf16x8*)bpl;
      oacc[n] = __builtin_amdgcn_mfma_f32_16x16x32_bf16(aw, bhv, oacc[n], 0, 0, 0);
      oacc[n] = __builtin_amdgcn_mfma_f32_16x16x32_bf16(aw, blv, oacc[n], 0, 0, 0);
    }
    asm volatile("s_waitcnt lgkmcnt(0)" ::: "memory");  // reads done before reuse
  }

  // ---- phase 6: store partials, one barrier, gather+sum, write global ----
#pragma unroll
  for (int n = 0; n < 4; ++n)
#pragma unroll
    for (int r = 0; r < 4; ++r)
      ex[w][quad * 4 + r][n * 16 + l16] = oacc[n][r];
  __syncthreads();
  {
    const int row = 2 * w + (lane >> 5);
    const int d = lane & 31;
    float v0 = 0.f, v1 = 0.f;
#pragma unroll
    for (int i = 0; i < WV; ++i) {
      v0 += ex[i][row][d];
      v1 += ex[i][row][d + 32];
    }
    const int off = ((b * NL + qbase + row) * NH + h) * ND + d;
    outg[off] = v0;
    outg[off + 32] = v1;
  }
}

extern "C" void kernel_launch(void* const* d_in, const int* in_sizes, int n_in,
                              void* d_out, int out_size, void* d_ws, size_t ws_size,
                              hipStream_t stream) {
  const float* q = (const float*)d_in[0];
  const float* k = (const float*)d_in[1];
  const float* v = (const float*)d_in[2];

  const size_t plane = (size_t)NB * NH * ND * NL;  // 3.15M elems, 6.29MB/plane
  __bf16* k_hi = (__bf16*)d_ws;
  __bf16* k_lo = k_hi + plane;
  __bf16* vt_hi = k_lo + plane;
  __bf16* vt_lo = vt_hi + plane;

  prep<<<NB * NH * (NL / 64), 256, 0, stream>>>(k, v, k_hi, k_lo, vt_hi, vt_lo);

  attn_poly<<<NB * NH * (NL / 16), 512, 0, stream>>>(
      q, k_hi, k_lo, vt_hi, vt_lo, (float*)d_out);
}

// Round 6
// 283.602 us; speedup vs baseline: 1.7471x; 1.7471x over previous
//
#include <hip/hip_runtime.h>
#include <hip/hip_bf16.h>

#define NB 2
#define NL 2048
#define NH 12
#define ND 64
#define NEWTON 6
#define WV 8            // waves per block
#define TPW 16          // key-tiles per wave = 128/WV

typedef __bf16 bf16x8 __attribute__((ext_vector_type(8)));
typedef __bf16 bf16x4 __attribute__((ext_vector_type(4)));
typedef float f32x4 __attribute__((ext_vector_type(4)));

// DPP row_ror reductions within each 16-lane row.
#define ROR_ADD(v, n)                                                         \
  (v) += __int_as_float(__builtin_amdgcn_update_dpp(                          \
      0, __float_as_int(v), 0x120 + (n), 0xF, 0xF, true))
#define ROR_MAX(v, n)                                                         \
  (v) = fmaxf((v), __int_as_float(__builtin_amdgcn_update_dpp(                \
                  0, __float_as_int(v), 0x120 + (n), 0xF, 0xF, true)))

__device__ __forceinline__ void split_bf16(float f, __bf16& hi, __bf16& lo) {
  __bf16 h = (__bf16)f;
  hi = h;
  lo = (__bf16)(f - (float)h);
}

// ---- prep: pack K and V into MFMA-fragment-linear order (1 KB wave loads) ----
// Kp[bh][kt(128)][chunk(2)][lane(64)][8]: lane(quad,l16) = K[key=16kt+l16][d=chunk*32+quad*8+j]
// Vp[bh][pi(64)][n(4)][lane(64)][8]:  lane(quad,l16) = V[key=16*kt(quad)+(quad&1)*8+j][d=n*16+l16]
//   where pair pi covers kt0=(pi>>3)*16+(pi&7) (quads 0,1) and kt1=kt0+8 (quads 2,3).
__global__ void prep(const float* __restrict__ k, const float* __restrict__ v,
                     __bf16* __restrict__ kp_hi, __bf16* __restrict__ kp_lo,
                     __bf16* __restrict__ vp_hi, __bf16* __restrict__ vp_lo) {
  __shared__ float vtile[16][65];
  const int blk = blockIdx.x;
  const int kt = blk & 127;
  const int bh = blk >> 7;
  const int h = bh % NH;
  const int b = bh / NH;
  const int lane = threadIdx.x;
  const int quad = lane >> 4;
  const int l16 = lane & 15;

  // --- K pack ---
  {
    const int key = kt * 16 + l16;
    const float* src = k + ((size_t)(b * NL + key) * NH + h) * ND + quad * 8;
    f32x4 a0 = *(const f32x4*)(src);
    f32x4 a1 = *(const f32x4*)(src + 4);
    f32x4 a2 = *(const f32x4*)(src + 32);
    f32x4 a3 = *(const f32x4*)(src + 36);
    bf16x8 h0, l0, h1, l1;
#pragma unroll
    for (int j = 0; j < 4; ++j) {
      __bf16 hb, lb;
      split_bf16(a0[j], hb, lb); h0[j] = hb;     l0[j] = lb;
      split_bf16(a1[j], hb, lb); h0[4 + j] = hb; l0[4 + j] = lb;
      split_bf16(a2[j], hb, lb); h1[j] = hb;     l1[j] = lb;
      split_bf16(a3[j], hb, lb); h1[4 + j] = hb; l1[4 + j] = lb;
    }
    const size_t basek = ((size_t)(bh * 128 + kt) * 2) * 512 + lane * 8;
    *(bf16x8*)(kp_hi + basek) = h0;
    *(bf16x8*)(kp_lo + basek) = l0;
    *(bf16x8*)(kp_hi + basek + 512) = h1;
    *(bf16x8*)(kp_lo + basek + 512) = l1;
  }

  // --- V tile -> LDS (coalesced) ---
  {
    const int krow = lane >> 2;
    const int seg = (lane & 3) * 16;
    const float* src = v + ((size_t)(b * NL + kt * 16 + krow) * NH + h) * ND + seg;
    f32x4 x0 = *(const f32x4*)(src);
    f32x4 x1 = *(const f32x4*)(src + 4);
    f32x4 x2 = *(const f32x4*)(src + 8);
    f32x4 x3 = *(const f32x4*)(src + 12);
#pragma unroll
    for (int j = 0; j < 4; ++j) {
      vtile[krow][seg + j] = x0[j];
      vtile[krow][seg + 4 + j] = x1[j];
      vtile[krow][seg + 8 + j] = x2[j];
      vtile[krow][seg + 12 + j] = x3[j];
    }
  }
  __syncthreads();

  // --- V pack ---
  {
    const int halfsel = (kt >> 3) & 1;
    const int pi = (kt >> 4) * 8 + (kt & 7);
    const int qt = 2 * halfsel + (quad & 1);
    const size_t vbase = ((size_t)bh * 64 + pi) * 4;
#pragma unroll
    for (int nn = 0; nn < 2; ++nn) {
      const int n = (quad >> 1) * 2 + nn;
      bf16x8 hv, lv;
#pragma unroll
      for (int j = 0; j < 8; ++j) {
        __bf16 hb, lb;
        split_bf16(vtile[(quad & 1) * 8 + j][n * 16 + l16], hb, lb);
        hv[j] = hb;
        lv[j] = lb;
      }
      const size_t off = ((vbase + n) * 64 + qt * 16 + l16) * 8;
      *(bf16x8*)(vp_hi + off) = hv;
      *(bf16x8*)(vp_lo + off) = lv;
    }
  }
}

// ---------------- main fused attention-poly kernel ----------------
__launch_bounds__(512, 4)
__global__ void attn_poly(const float* __restrict__ qg,
                          const __bf16* __restrict__ kp_hi,
                          const __bf16* __restrict__ kp_lo,
                          const __bf16* __restrict__ vp_hi,
                          const __bf16* __restrict__ vp_lo,
                          float* __restrict__ outg) {
  __shared__ __align__(16) float ex[WV][16][68];  // phase5 slabs + phase6 partials
  __shared__ float redmax[WV][16];
  __shared__ float2 redq[2][WV][16];

  const int tid = threadIdx.x;
  const int w = tid >> 6;
  const int lane = tid & 63;
  const int quad = lane >> 4;
  const int l16 = lane & 15;

  const int blk = blockIdx.x;
  const int qt = blk & 127;
  const int bh = blk >> 7;
  const int h = bh % NH;
  const int b = bh / NH;
  const int qbase = qt * 16;

  // ---- Q fragments: fp32 * 0.125 -> bf16 hi/lo ----
  bf16x8 qhi0, qlo0, qhi1, qlo1;
  {
    const float* qp = qg + ((b * NL + qbase + l16) * NH + h) * ND + quad * 8;
    f32x4 a0 = *(const f32x4*)(qp);
    f32x4 a1 = *(const f32x4*)(qp + 4);
    f32x4 a2 = *(const f32x4*)(qp + 32);
    f32x4 a3 = *(const f32x4*)(qp + 36);
#pragma unroll
    for (int j = 0; j < 4; ++j) {
      __bf16 hb, lb;
      split_bf16(a0[j] * 0.125f, hb, lb); qhi0[j] = hb;     qlo0[j] = lb;
      split_bf16(a1[j] * 0.125f, hb, lb); qhi0[4 + j] = hb; qlo0[4 + j] = lb;
      split_bf16(a2[j] * 0.125f, hb, lb); qhi1[j] = hb;     qlo1[j] = lb;
      split_bf16(a3[j] * 0.125f, hb, lb); qhi1[4 + j] = hb; qlo1[4 + j] = lb;
    }
  }

  // ---- phase 1: S = (Q/8) Kt, packed K: every load is 1 KB contiguous ----
  float sc[TPW][4];
  {
    const __bf16* kbh = kp_hi + (size_t)bh * 131072;  // 128kt * 2 * 512
    const __bf16* kbl = kp_lo + (size_t)bh * 131072;
#pragma unroll
    for (int t = 0; t < TPW; ++t) {
      const int kt = w + WV * t;
      const size_t o = (size_t)kt * 1024 + lane * 8;
      bf16x8 khi0 = *(const bf16x8*)(kbh + o);
      bf16x8 khi1 = *(const bf16x8*)(kbh + o + 512);
      bf16x8 klo0 = *(const bf16x8*)(kbl + o);
      bf16x8 klo1 = *(const bf16x8*)(kbl + o + 512);
      f32x4 acc = {0.f, 0.f, 0.f, 0.f};
      acc = __builtin_amdgcn_mfma_f32_16x16x32_bf16(qhi0, khi0, acc, 0, 0, 0);
      acc = __builtin_amdgcn_mfma_f32_16x16x32_bf16(qhi1, khi1, acc, 0, 0, 0);
      acc = __builtin_amdgcn_mfma_f32_16x16x32_bf16(qhi0, klo0, acc, 0, 0, 0);
      acc = __builtin_amdgcn_mfma_f32_16x16x32_bf16(qhi1, klo1, acc, 0, 0, 0);
      acc = __builtin_amdgcn_mfma_f32_16x16x32_bf16(qlo0, khi0, acc, 0, 0, 0);
      acc = __builtin_amdgcn_mfma_f32_16x16x32_bf16(qlo1, khi1, acc, 0, 0, 0);
#pragma unroll
      for (int r = 0; r < 4; ++r) sc[t][r] = acc[r];
    }
  }

  // ---- phase 2: row max -> cr[r] = -max - 1 ----
  float cr[4];
  {
    float mx[4];
#pragma unroll
    for (int r = 0; r < 4; ++r) {
      float m = sc[0][r];
#pragma unroll
      for (int t = 1; t < TPW; ++t) m = fmaxf(m, sc[t][r]);
      ROR_MAX(m, 8); ROR_MAX(m, 4); ROR_MAX(m, 2); ROR_MAX(m, 1);
      mx[r] = m;
    }
    if (l16 < 4) {
      float v = (l16 == 0) ? mx[0] : (l16 == 1) ? mx[1] : (l16 == 2) ? mx[2] : mx[3];
      redmax[w][quad * 4 + l16] = v;
    }
    __syncthreads();
#pragma unroll
    for (int r = 0; r < 4; ++r) {
      float m = redmax[0][quad * 4 + r];
#pragma unroll
      for (int i = 1; i < WV; ++i) m = fmaxf(m, redmax[i][quad * 4 + r]);
      cr[r] = -m - 1.0f;
    }
  }

  // ---- phase 3: Newton x6 ----
  for (int it = 0; it < NEWTON; ++it) {
    const int par = it & 1;
    float ps[4] = {0.f, 0.f, 0.f, 0.f};
    float psd[4] = {0.f, 0.f, 0.f, 0.f};
#pragma unroll
    for (int t = 0; t < TPW; ++t) {
#pragma unroll
      for (int r = 0; r < 4; ++r) {
        float y = -(sc[t][r] + cr[r]);
        float r1 = __builtin_amdgcn_rcpf(y);
        float r2 = r1 * r1;
        ps[r] += r2;
        psd[r] = fmaf(r2, r1, psd[r]);
      }
    }
#pragma unroll
    for (int r = 0; r < 4; ++r) {
      ROR_ADD(ps[r], 8);  ROR_ADD(ps[r], 4);  ROR_ADD(ps[r], 2);  ROR_ADD(ps[r], 1);
      ROR_ADD(psd[r], 8); ROR_ADD(psd[r], 4); ROR_ADD(psd[r], 2); ROR_ADD(psd[r], 1);
    }
    if (l16 < 4) {
      float a = (l16 == 0) ? ps[0] : (l16 == 1) ? ps[1] : (l16 == 2) ? ps[2] : ps[3];
      float d = (l16 == 0) ? psd[0] : (l16 == 1) ? psd[1] : (l16 == 2) ? psd[2] : psd[3];
      redq[par][w][quad * 4 + l16] = make_float2(a, d);
    }
    __syncthreads();
#pragma unroll
    for (int r = 0; r < 4; ++r) {
      float pst = 0.f, psdt = 0.f;
#pragma unroll
      for (int i = 0; i < WV; ++i) {
        float2 p = redq[par][i][quad * 4 + r];
        pst += p.x;
        psdt += p.y;
      }
      cr[r] -= (pst - 1.0f) * __builtin_amdgcn_rcpf(2.0f * psdt + 1e-8f);
    }
  }

  // ---- phase 4: weights = 1/y^2 ----
#pragma unroll
  for (int t = 0; t < TPW; ++t) {
#pragma unroll
    for (int r = 0; r < 4; ++r) {
      float y = -(sc[t][r] + cr[r]);
      float r1 = __builtin_amdgcn_rcpf(y);
      sc[t][r] = r1 * r1;
    }
  }

  // ---- phase 5: O_partial = W * (Vhi + Vlo), packed V: 1 KB contiguous loads ----
  f32x4 oacc[4];
#pragma unroll
  for (int n = 0; n < 4; ++n) oacc[n] = (f32x4){0.f, 0.f, 0.f, 0.f};
  float* myslab = &ex[w][0][0];
  const __bf16* vpbh = vp_hi + (size_t)bh * 131072;  // 64pi * 4n * 512
  const __bf16* vpbl = vp_lo + (size_t)bh * 131072;
#pragma unroll
  for (int p = 0; p < 8; ++p) {
#pragma unroll
    for (int ts = 0; ts < 2; ++ts) {
      const int t = 2 * p + ts;
#pragma unroll
      for (int r = 0; r < 4; ++r)
        myslab[(quad * 4 + r) * 68 + ts * 16 + l16] = sc[t][r];
    }
    asm volatile("s_waitcnt lgkmcnt(0)" ::: "memory");
    f32x4 w0 = *(const f32x4*)(myslab + l16 * 68 + quad * 8);
    f32x4 w1 = *(const f32x4*)(myslab + l16 * 68 + quad * 8 + 4);
    bf16x8 aw;
#pragma unroll
    for (int j = 0; j < 4; ++j) {
      aw[j] = (__bf16)w0[j];
      aw[4 + j] = (__bf16)w1[j];
    }
    const size_t vo = ((size_t)(p * 8 + w) * 4) * 512 + lane * 8;
#pragma unroll
    for (int n = 0; n < 4; ++n) {
      bf16x8 bhv = *(const bf16x8*)(vpbh + vo + n * 512);
      bf16x8 blv = *(const bf16x8*)(vpbl + vo + n * 512);
      oacc[n] = __builtin_amdgcn_mfma_f32_16x16x32_bf16(aw, bhv, oacc[n], 0, 0, 0);
      oacc[n] = __builtin_amdgcn_mfma_f32_16x16x32_bf16(aw, blv, oacc[n], 0, 0, 0);
    }
    asm volatile("s_waitcnt lgkmcnt(0)" ::: "memory");
  }

  // ---- phase 6: reduce partials across waves, write global ----
#pragma unroll
  for (int n = 0; n < 4; ++n)
#pragma unroll
    for (int r = 0; r < 4; ++r)
      ex[w][quad * 4 + r][n * 16 + l16] = oacc[n][r];
  __syncthreads();
  {
    const int row = 2 * w + (lane >> 5);
    const int d = lane & 31;
    float v0 = 0.f, v1 = 0.f;
#pragma unroll
    for (int i = 0; i < WV; ++i) {
      v0 += ex[i][row][d];
      v1 += ex[i][row][d + 32];
    }
    const int off = ((b * NL + qbase + row) * NH + h) * ND + d;
    outg[off] = v0;
    outg[off + 32] = v1;
  }
}

extern "C" void kernel_launch(void* const* d_in, const int* in_sizes, int n_in,
                              void* d_out, int out_size, void* d_ws, size_t ws_size,
                              hipStream_t stream) {
  const float* q = (const float*)d_in[0];
  const float* k = (const float*)d_in[1];
  const float* v = (const float*)d_in[2];

  const size_t plane = (size_t)NB * NH * ND * NL;  // 3.15M elems, 6.29MB/plane
  __bf16* kp_hi = (__bf16*)d_ws;
  __bf16* kp_lo = kp_hi + plane;
  __bf16* vp_hi = kp_lo + plane;
  __bf16* vp_lo = vp_hi + plane;

  prep<<<NB * NH * 128, 64, 0, stream>>>(k, v, kp_hi, kp_lo, vp_hi, vp_lo);

  attn_poly<<<NB * NH * (NL / 16), 512, 0, stream>>>(
      q, kp_hi, kp_lo, vp_hi, vp_lo, (float*)d_out);
}

// Round 7
// 269.393 us; speedup vs baseline: 1.8392x; 1.0527x over previous
//
#include <hip/hip_runtime.h>
#include <hip/hip_bf16.h>

#define NB 2
#define NL 2048
#define NH 12
#define ND 64
#define NEWTON 6
#define WV 8            // waves per block
#define TPW 16          // key-tiles per wave = 128/WV
#define KPAD 772        // 12*64+4: 16B-aligned rows, <=2-way LDS conflicts

typedef __bf16 bf16x8 __attribute__((ext_vector_type(8)));
typedef float f32x4 __attribute__((ext_vector_type(4)));
typedef float f32x2 __attribute__((ext_vector_type(2)));

// DPP row_ror reductions within each 16-lane row.
#define ROR_ADD(v, n)                                                         \
  (v) += __int_as_float(__builtin_amdgcn_update_dpp(                          \
      0, __float_as_int(v), 0x120 + (n), 0xF, 0xF, true))
#define ROR_MAX(v, n)                                                         \
  (v) = fmaxf((v), __int_as_float(__builtin_amdgcn_update_dpp(                \
                  0, __float_as_int(v), 0x120 + (n), 0xF, 0xF, true)))

__device__ __forceinline__ void split_bf16(float f, __bf16& hi, __bf16& lo) {
  __bf16 h = (__bf16)f;
  hi = h;
  lo = (__bf16)(f - (float)h);
}

// ---- prep: coalesced load of one (b, 16-key tile) for ALL heads -> pack ----
// Kp[bh][kt(128)][chunk(2)][lane(64)][8] ; Vp[bh][pi(64)][n(4)][lane(64)][8]
// (layouts identical to round-6, which is correctness-verified)
__global__ __launch_bounds__(256) void prep(
    const float* __restrict__ kg, const float* __restrict__ vg,
    __bf16* __restrict__ kp_hi, __bf16* __restrict__ kp_lo,
    __bf16* __restrict__ vp_hi, __bf16* __restrict__ vp_lo) {
  __shared__ __align__(16) float kv[16 * KPAD];  // 49.4 KB
  const int blk = blockIdx.x;
  const int kt = blk & 127;
  const int b = blk >> 7;
  const int t = threadIdx.x;
  const int w = t >> 6;
  const int lane = t & 63;
  const int quad = lane >> 4;
  const int l16 = lane & 15;
  const size_t srcbase = ((size_t)(b * NL + kt * 16)) * (NH * ND);

  // ================= K round =================
#pragma unroll
  for (int i = 0; i < 12; ++i) {
    int f = i * 1024 + t * 4;
    f32x4 val = *(const f32x4*)(kg + srcbase + f);
    int key = f / 768;
    int rem = f - key * 768;
    *(f32x4*)(&kv[key * KPAD + rem]) = val;
  }
  __syncthreads();
#pragma unroll
  for (int hh = 0; hh < 3; ++hh) {
    const int h = w * 3 + hh;
    const float* p = &kv[l16 * KPAD + h * 64 + quad * 8];
    f32x4 a0 = *(const f32x4*)(p);
    f32x4 a1 = *(const f32x4*)(p + 4);
    f32x4 a2 = *(const f32x4*)(p + 32);
    f32x4 a3 = *(const f32x4*)(p + 36);
    bf16x8 h0, l0, h1, l1;
#pragma unroll
    for (int j = 0; j < 4; ++j) {
      __bf16 hb, lb;
      split_bf16(a0[j], hb, lb); h0[j] = hb;     l0[j] = lb;
      split_bf16(a1[j], hb, lb); h0[4 + j] = hb; l0[4 + j] = lb;
      split_bf16(a2[j], hb, lb); h1[j] = hb;     l1[j] = lb;
      split_bf16(a3[j], hb, lb); h1[4 + j] = hb; l1[4 + j] = lb;
    }
    const size_t basek =
        ((size_t)((b * NH + h) * 128 + kt) * 2) * 512 + lane * 8;
    *(bf16x8*)(kp_hi + basek) = h0;
    *(bf16x8*)(kp_lo + basek) = l0;
    *(bf16x8*)(kp_hi + basek + 512) = h1;
    *(bf16x8*)(kp_lo + basek + 512) = l1;
  }

  // ================= V round =================
  __syncthreads();  // pack reads done before overwrite
#pragma unroll
  for (int i = 0; i < 12; ++i) {
    int f = i * 1024 + t * 4;
    f32x4 val = *(const f32x4*)(vg + srcbase + f);
    int key = f / 768;
    int rem = f - key * 768;
    *(f32x4*)(&kv[key * KPAD + rem]) = val;
  }
  __syncthreads();
  {
    const int halfsel = (kt >> 3) & 1;
    const int pi = (kt >> 4) * 8 + (kt & 7);
    const int q2 = quad & 1;           // key-local half (j base = q2*8)
    const int nhalf = quad >> 1;       // n in {2*nhalf, 2*nhalf+1}
    const int qdst = 2 * halfsel + q2;
#pragma unroll
    for (int hh = 0; hh < 3; ++hh) {
      const int h = w * 3 + hh;
#pragma unroll
      for (int nn = 0; nn < 2; ++nn) {
        const int n = nhalf * 2 + nn;
        bf16x8 hv, lv;
#pragma unroll
        for (int j = 0; j < 8; ++j) {
          __bf16 hb, lb;
          split_bf16(kv[(q2 * 8 + j) * KPAD + h * 64 + n * 16 + l16], hb, lb);
          hv[j] = hb;
          lv[j] = lb;
        }
        const size_t off =
            ((((size_t)(b * NH + h) * 64 + pi) * 4 + n) * 64 + qdst * 16 + l16) * 8;
        *(bf16x8*)(vp_hi + off) = hv;
        *(bf16x8*)(vp_lo + off) = lv;
      }
    }
  }
}

// ---------------- main fused attention-poly kernel ----------------
__launch_bounds__(512, 4)
__global__ void attn_poly(const float* __restrict__ qg,
                          const __bf16* __restrict__ kp_hi,
                          const __bf16* __restrict__ kp_lo,
                          const __bf16* __restrict__ vp_hi,
                          const __bf16* __restrict__ vp_lo,
                          float* __restrict__ outg) {
  __shared__ __align__(16) float ex[WV][16][68];
  __shared__ float redmax[WV][16];
  __shared__ f32x2 redq[2][WV][16];   // (Sum y^-2, Sum y^-3) per wave x row

  const int tid = threadIdx.x;
  const int w = tid >> 6;
  const int lane = tid & 63;
  const int quad = lane >> 4;
  const int l16 = lane & 15;

  const int blk = blockIdx.x;
  const int qt = blk & 127;
  const int bh = blk >> 7;
  const int h = bh % NH;
  const int b = bh / NH;
  const int qbase = qt * 16;

  // ---- Q fragments: fp32 * 0.125 -> bf16 hi/lo ----
  bf16x8 qhi0, qlo0, qhi1, qlo1;
  {
    const float* qp = qg + ((b * NL + qbase + l16) * NH + h) * ND + quad * 8;
    f32x4 a0 = *(const f32x4*)(qp);
    f32x4 a1 = *(const f32x4*)(qp + 4);
    f32x4 a2 = *(const f32x4*)(qp + 32);
    f32x4 a3 = *(const f32x4*)(qp + 36);
#pragma unroll
    for (int j = 0; j < 4; ++j) {
      __bf16 hb, lb;
      split_bf16(a0[j] * 0.125f, hb, lb); qhi0[j] = hb;     qlo0[j] = lb;
      split_bf16(a1[j] * 0.125f, hb, lb); qhi0[4 + j] = hb; qlo0[4 + j] = lb;
      split_bf16(a2[j] * 0.125f, hb, lb); qhi1[j] = hb;     qlo1[j] = lb;
      split_bf16(a3[j] * 0.125f, hb, lb); qhi1[4 + j] = hb; qlo1[4 + j] = lb;
    }
  }

  // ---- phase 1: S = (Q/8) Kt ; sc2[t][j] = rows (quad*4+2j, +2j+1), col l16 ----
  f32x2 sc2[TPW][2];
  {
    const __bf16* kbh = kp_hi + (size_t)bh * 131072;
    const __bf16* kbl = kp_lo + (size_t)bh * 131072;
#pragma unroll
    for (int t = 0; t < TPW; ++t) {
      const int ktile = w + WV * t;
      const size_t o = (size_t)ktile * 1024 + lane * 8;
      bf16x8 khi0 = *(const bf16x8*)(kbh + o);
      bf16x8 khi1 = *(const bf16x8*)(kbh + o + 512);
      bf16x8 klo0 = *(const bf16x8*)(kbl + o);
      bf16x8 klo1 = *(const bf16x8*)(kbl + o + 512);
      f32x4 acc = {0.f, 0.f, 0.f, 0.f};
      acc = __builtin_amdgcn_mfma_f32_16x16x32_bf16(qhi0, khi0, acc, 0, 0, 0);
      acc = __builtin_amdgcn_mfma_f32_16x16x32_bf16(qhi1, khi1, acc, 0, 0, 0);
      acc = __builtin_amdgcn_mfma_f32_16x16x32_bf16(qhi0, klo0, acc, 0, 0, 0);
      acc = __builtin_amdgcn_mfma_f32_16x16x32_bf16(qhi1, klo1, acc, 0, 0, 0);
      acc = __builtin_amdgcn_mfma_f32_16x16x32_bf16(qlo0, khi0, acc, 0, 0, 0);
      acc = __builtin_amdgcn_mfma_f32_16x16x32_bf16(qlo1, khi1, acc, 0, 0, 0);
      sc2[t][0] = __builtin_shufflevector(acc, acc, 0, 1);
      sc2[t][1] = __builtin_shufflevector(acc, acc, 2, 3);
    }
  }

  // ---- phase 2: row max -> cr2 = -max - 1 ----
  f32x2 cr2[2];
  {
    f32x2 mx2[2] = {sc2[0][0], sc2[0][1]};
#pragma unroll
    for (int t = 1; t < TPW; ++t) {
#pragma unroll
      for (int j = 0; j < 2; ++j) {
        mx2[j].x = fmaxf(mx2[j].x, sc2[t][j].x);
        mx2[j].y = fmaxf(mx2[j].y, sc2[t][j].y);
      }
    }
#pragma unroll
    for (int j = 0; j < 2; ++j) {
      ROR_MAX(mx2[j].x, 8); ROR_MAX(mx2[j].x, 4); ROR_MAX(mx2[j].x, 2); ROR_MAX(mx2[j].x, 1);
      ROR_MAX(mx2[j].y, 8); ROR_MAX(mx2[j].y, 4); ROR_MAX(mx2[j].y, 2); ROR_MAX(mx2[j].y, 1);
    }
    if (l16 < 4) {
      float v = (l16 == 0) ? mx2[0].x : (l16 == 1) ? mx2[0].y
              : (l16 == 2) ? mx2[1].x : mx2[1].y;
      redmax[w][quad * 4 + l16] = v;
    }
    __syncthreads();
    float crs[4];
#pragma unroll
    for (int r = 0; r < 4; ++r) {
      float m = redmax[l16 & 7][quad * 4 + r];   // distributed: lane reads one wave's partial
      ROR_MAX(m, 4); ROR_MAX(m, 2); ROR_MAX(m, 1);  // sums 8 consecutive (mod 16) = all 8 waves
      crs[r] = -m - 1.0f;
    }
    cr2[0].x = crs[0]; cr2[0].y = crs[1];
    cr2[1].x = crs[2]; cr2[1].y = crs[3];
  }

  // ---- phase 3: Newton x6 (packed f32, one barrier/iter) ----
  for (int it = 0; it < NEWTON; ++it) {
    const int par = it & 1;
    f32x2 ps2[2] = {{0.f, 0.f}, {0.f, 0.f}};
    f32x2 psd2[2] = {{0.f, 0.f}, {0.f, 0.f}};
#pragma unroll
    for (int t = 0; t < TPW; ++t) {
#pragma unroll
      for (int j = 0; j < 2; ++j) {
        f32x2 y = -(sc2[t][j] + cr2[j]);
        f32x2 r1;
        r1.x = __builtin_amdgcn_rcpf(y.x);
        r1.y = __builtin_amdgcn_rcpf(y.y);
        f32x2 r2 = r1 * r1;
        ps2[j] += r2;
        psd2[j] += r2 * r1;
      }
    }
#pragma unroll
    for (int j = 0; j < 2; ++j) {
      ROR_ADD(ps2[j].x, 8);  ROR_ADD(ps2[j].x, 4);  ROR_ADD(ps2[j].x, 2);  ROR_ADD(ps2[j].x, 1);
      ROR_ADD(ps2[j].y, 8);  ROR_ADD(ps2[j].y, 4);  ROR_ADD(ps2[j].y, 2);  ROR_ADD(ps2[j].y, 1);
      ROR_ADD(psd2[j].x, 8); ROR_ADD(psd2[j].x, 4); ROR_ADD(psd2[j].x, 2); ROR_ADD(psd2[j].x, 1);
      ROR_ADD(psd2[j].y, 8); ROR_ADD(psd2[j].y, 4); ROR_ADD(psd2[j].y, 2); ROR_ADD(psd2[j].y, 1);
    }
    if (l16 < 4) {
      float a = (l16 == 0) ? ps2[0].x : (l16 == 1) ? ps2[0].y
              : (l16 == 2) ? ps2[1].x : ps2[1].y;
      float d = (l16 == 0) ? psd2[0].x : (l16 == 1) ? psd2[0].y
              : (l16 == 2) ? psd2[1].x : psd2[1].y;
      redq[par][w][quad * 4 + l16] = f32x2{a, d};
    }
    __syncthreads();
    float crs[4];
#pragma unroll
    for (int r = 0; r < 4; ++r) {
      f32x2 v = redq[par][l16 & 7][quad * 4 + r];
      ROR_ADD(v.x, 4); ROR_ADD(v.x, 2); ROR_ADD(v.x, 1);
      ROR_ADD(v.y, 4); ROR_ADD(v.y, 2); ROR_ADD(v.y, 1);
      float c = (r < 2) ? ((r & 1) ? cr2[0].y : cr2[0].x)
                        : ((r & 1) ? cr2[1].y : cr2[1].x);
      crs[r] = c - (v.x - 1.0f) * __builtin_amdgcn_rcpf(2.0f * v.y + 1e-8f);
    }
    cr2[0].x = crs[0]; cr2[0].y = crs[1];
    cr2[1].x = crs[2]; cr2[1].y = crs[3];
  }

  // ---- phase 5: weights computed on the fly; O_partial = W * (Vhi + Vlo) ----
  f32x4 oacc[4];
#pragma unroll
  for (int n = 0; n < 4; ++n) oacc[n] = (f32x4){0.f, 0.f, 0.f, 0.f};
  float* myslab = &ex[w][0][0];
  const __bf16* vpbh = vp_hi + (size_t)bh * 131072;
  const __bf16* vpbl = vp_lo + (size_t)bh * 131072;
#pragma unroll
  for (int p = 0; p < 8; ++p) {
#pragma unroll
    for (int ts = 0; ts < 2; ++ts) {
      const int t = 2 * p + ts;
#pragma unroll
      for (int j = 0; j < 2; ++j) {
        f32x2 y = -(sc2[t][j] + cr2[j]);
        f32x2 u;
        u.x = __builtin_amdgcn_rcpf(y.x);
        u.y = __builtin_amdgcn_rcpf(y.y);
        f32x2 wgt = u * u;
        myslab[(quad * 4 + 2 * j) * 68 + ts * 16 + l16] = wgt.x;
        myslab[(quad * 4 + 2 * j + 1) * 68 + ts * 16 + l16] = wgt.y;
      }
    }
    asm volatile("s_waitcnt lgkmcnt(0)" ::: "memory");  // wave-internal exchange
    f32x4 w0 = *(const f32x4*)(myslab + l16 * 68 + quad * 8);
    f32x4 w1 = *(const f32x4*)(myslab + l16 * 68 + quad * 8 + 4);
    bf16x8 aw;
#pragma unroll
    for (int j = 0; j < 4; ++j) {
      aw[j] = (__bf16)w0[j];
      aw[4 + j] = (__bf16)w1[j];
    }
    const size_t vo = ((size_t)(p * 8 + w) * 4) * 512 + lane * 8;
#pragma unroll
    for (int n = 0; n < 4; ++n) {
      bf16x8 bhv = *(const bf16x8*)(vpbh + vo + n * 512);
      bf16x8 blv = *(const bf16x8*)(vpbl + vo + n * 512);
      oacc[n] = __builtin_amdgcn_mfma_f32_16x16x32_bf16(aw, bhv, oacc[n], 0, 0, 0);
      oacc[n] = __builtin_amdgcn_mfma_f32_16x16x32_bf16(aw, blv, oacc[n], 0, 0, 0);
    }
    asm volatile("s_waitcnt lgkmcnt(0)" ::: "memory");
  }

  // ---- phase 6: reduce partials across waves, write global ----
#pragma unroll
  for (int n = 0; n < 4; ++n)
#pragma unroll
    for (int r = 0; r < 4; ++r)
      ex[w][quad * 4 + r][n * 16 + l16] = oacc[n][r];
  __syncthreads();
  {
    const int row = 2 * w + (lane >> 5);
    const int d = lane & 31;
    float v0 = 0.f, v1 = 0.f;
#pragma unroll
    for (int i = 0; i < WV; ++i) {
      v0 += ex[i][row][d];
      v1 += ex[i][row][d + 32];
    }
    const int off = ((b * NL + qbase + row) * NH + h) * ND + d;
    outg[off] = v0;
    outg[off + 32] = v1;
  }
}

extern "C" void kernel_launch(void* const* d_in, const int* in_sizes, int n_in,
                              void* d_out, int out_size, void* d_ws, size_t ws_size,
                              hipStream_t stream) {
  const float* q = (const float*)d_in[0];
  const float* k = (const float*)d_in[1];
  const float* v = (const float*)d_in[2];

  const size_t plane = (size_t)NB * NH * ND * NL;  // 3.15M elems, 6.29MB/plane
  __bf16* kp_hi = (__bf16*)d_ws;
  __bf16* kp_lo = kp_hi + plane;
  __bf16* vp_hi = kp_lo + plane;
  __bf16* vp_lo = vp_hi + plane;

  prep<<<NB * 128, 256, 0, stream>>>(k, v, kp_hi, kp_lo, vp_hi, vp_lo);

  attn_poly<<<NB * NH * (NL / 16), 512, 0, stream>>>(
      q, kp_hi, kp_lo, vp_hi, vp_lo, (float*)d_out);
}

// Round 8
// 266.570 us; speedup vs baseline: 1.8587x; 1.0106x over previous
//
#include <hip/hip_runtime.h>
#include <hip/hip_bf16.h>

#define NB 2
#define NL 2048
#define NH 12
#define ND 64
#define NEWTON 6
#define WV 8            // waves per block (attn)
#define TPW 16          // key-tiles per wave = 128/WV

typedef __bf16 bf16x8 __attribute__((ext_vector_type(8)));
typedef float f32x4 __attribute__((ext_vector_type(4)));
typedef float f32x2 __attribute__((ext_vector_type(2)));

// DPP row_ror reductions within each 16-lane row.
#define ROR_ADD(v, n)                                                         \
  (v) += __int_as_float(__builtin_amdgcn_update_dpp(                          \
      0, __float_as_int(v), 0x120 + (n), 0xF, 0xF, true))
#define ROR_MAX(v, n)                                                         \
  (v) = fmaxf((v), __int_as_float(__builtin_amdgcn_update_dpp(                \
                  0, __float_as_int(v), 0x120 + (n), 0xF, 0xF, true)))

__device__ __forceinline__ void split_bf16(float f, __bf16& hi, __bf16& lo) {
  __bf16 h = (__bf16)f;
  hi = h;
  lo = (__bf16)(f - (float)h);
}

// ---- prep: block = (b, kt16, head-group of 4). 768 blocks, 256 thr, 33 KB LDS.
// Kp[bh][kt(128)][chunk(2)][lane(64)][8] ; Vp[bh][pi(64)][n(4)][lane(64)][8]
// (identical output layouts to round-6/7, which are correctness-verified)
__global__ __launch_bounds__(256) void prep(
    const float* __restrict__ kg, const float* __restrict__ vg,
    __bf16* __restrict__ kp_hi, __bf16* __restrict__ kp_lo,
    __bf16* __restrict__ vp_hi, __bf16* __restrict__ vp_lo) {
  __shared__ __align__(16) float kv[2][16][260];  // [K/V][key][4 heads x 64 d]
  const int blk = blockIdx.x;
  const int hg = blk % 3;
  const int kt = (blk / 3) & 127;
  const int b = blk / 384;
  const int t = threadIdx.x;
  const int w = t >> 6;           // wave 0..3 == local head
  const int lane = t & 63;
  const int quad = lane >> 4;
  const int l16 = lane & 15;

  // ---- load K and V tiles (each wave-load covers exactly one 1 KB key segment)
#pragma unroll
  for (int i = 0; i < 4; ++i) {
    const int f = i * 1024 + t * 4;
    const int key = f >> 8;
    const int rem = f & 255;
    const size_t src =
        (size_t)(b * NL + kt * 16 + key) * (NH * ND) + hg * 256 + rem;
    *(f32x4*)(&kv[0][key][rem]) = *(const f32x4*)(kg + src);
    *(f32x4*)(&kv[1][key][rem]) = *(const f32x4*)(vg + src);
  }
  __syncthreads();

  const int h = hg * 4 + w;

  // ---- K pack (wave w = local head w) ----
  {
    const float* p = &kv[0][l16][w * 64 + quad * 8];
    f32x4 a0 = *(const f32x4*)(p);
    f32x4 a1 = *(const f32x4*)(p + 4);
    f32x4 a2 = *(const f32x4*)(p + 32);
    f32x4 a3 = *(const f32x4*)(p + 36);
    bf16x8 h0, l0, h1, l1;
#pragma unroll
    for (int j = 0; j < 4; ++j) {
      __bf16 hb, lb;
      split_bf16(a0[j], hb, lb); h0[j] = hb;     l0[j] = lb;
      split_bf16(a1[j], hb, lb); h0[4 + j] = hb; l0[4 + j] = lb;
      split_bf16(a2[j], hb, lb); h1[j] = hb;     l1[j] = lb;
      split_bf16(a3[j], hb, lb); h1[4 + j] = hb; l1[4 + j] = lb;
    }
    const size_t basek =
        ((size_t)((b * NH + h) * 128 + kt) * 2) * 512 + lane * 8;
    *(bf16x8*)(kp_hi + basek) = h0;
    *(bf16x8*)(kp_lo + basek) = l0;
    *(bf16x8*)(kp_hi + basek + 512) = h1;
    *(bf16x8*)(kp_lo + basek + 512) = l1;
  }

  // ---- V pack (wave w = local head w) ----
  {
    const int halfsel = (kt >> 3) & 1;
    const int pi = (kt >> 4) * 8 + (kt & 7);
    const int q2 = quad & 1;
    const int nhalf = quad >> 1;
    const int qdst = 2 * halfsel + q2;
#pragma unroll
    for (int nn = 0; nn < 2; ++nn) {
      const int n = nhalf * 2 + nn;
      bf16x8 hv, lv;
#pragma unroll
      for (int j = 0; j < 8; ++j) {
        __bf16 hb, lb;
        split_bf16(kv[1][q2 * 8 + j][w * 64 + n * 16 + l16], hb, lb);
        hv[j] = hb;
        lv[j] = lb;
      }
      const size_t off =
          ((((size_t)(b * NH + h) * 64 + pi) * 4 + n) * 64 + qdst * 16 + l16) * 8;
      *(bf16x8*)(vp_hi + off) = hv;
      *(bf16x8*)(vp_lo + off) = lv;
    }
  }
}

// ---------------- main fused attention-poly kernel ----------------
__launch_bounds__(512, 4)
__global__ void attn_poly(const float* __restrict__ qg,
                          const __bf16* __restrict__ kp_hi,
                          const __bf16* __restrict__ kp_lo,
                          const __bf16* __restrict__ vp_hi,
                          const __bf16* __restrict__ vp_lo,
                          float* __restrict__ outg) {
  __shared__ __align__(16) float ex[WV][16][68];
  __shared__ float redmax[WV][17];     // +1 pad: kills 8-way read conflicts
  __shared__ f32x2 redq[2][WV][17];    // (Sum y^-2, Sum y^-3), padded row

  const int tid = threadIdx.x;
  const int w = tid >> 6;
  const int lane = tid & 63;
  const int quad = lane >> 4;
  const int l16 = lane & 15;

  const int blk = blockIdx.x;
  const int qt = blk & 127;
  const int bh = blk >> 7;
  const int h = bh % NH;
  const int b = bh / NH;
  const int qbase = qt * 16;

  // ---- Q fragments: fp32 * 0.125 -> bf16 hi/lo ----
  bf16x8 qhi0, qlo0, qhi1, qlo1;
  {
    const float* qp = qg + ((b * NL + qbase + l16) * NH + h) * ND + quad * 8;
    f32x4 a0 = *(const f32x4*)(qp);
    f32x4 a1 = *(const f32x4*)(qp + 4);
    f32x4 a2 = *(const f32x4*)(qp + 32);
    f32x4 a3 = *(const f32x4*)(qp + 36);
#pragma unroll
    for (int j = 0; j < 4; ++j) {
      __bf16 hb, lb;
      split_bf16(a0[j] * 0.125f, hb, lb); qhi0[j] = hb;     qlo0[j] = lb;
      split_bf16(a1[j] * 0.125f, hb, lb); qhi0[4 + j] = hb; qlo0[4 + j] = lb;
      split_bf16(a2[j] * 0.125f, hb, lb); qhi1[j] = hb;     qlo1[j] = lb;
      split_bf16(a3[j] * 0.125f, hb, lb); qhi1[4 + j] = hb; qlo1[4 + j] = lb;
    }
  }

  // ---- phase 1: S = (Q/8) Kt ; y2[t][j] holds rows (quad*4+2j, +2j+1), col l16
  f32x2 y2[TPW][2];   // first scores, then y = -(s + c) maintained in place
  {
    const __bf16* kbh = kp_hi + (size_t)bh * 131072;
    const __bf16* kbl = kp_lo + (size_t)bh * 131072;
#pragma unroll
    for (int t = 0; t < TPW; ++t) {
      const int ktile = w + WV * t;
      const size_t o = (size_t)ktile * 1024 + lane * 8;
      bf16x8 khi0 = *(const bf16x8*)(kbh + o);
      bf16x8 khi1 = *(const bf16x8*)(kbh + o + 512);
      bf16x8 klo0 = *(const bf16x8*)(kbl + o);
      bf16x8 klo1 = *(const bf16x8*)(kbl + o + 512);
      f32x4 acc = {0.f, 0.f, 0.f, 0.f};
      acc = __builtin_amdgcn_mfma_f32_16x16x32_bf16(qhi0, khi0, acc, 0, 0, 0);
      acc = __builtin_amdgcn_mfma_f32_16x16x32_bf16(qhi1, khi1, acc, 0, 0, 0);
      acc = __builtin_amdgcn_mfma_f32_16x16x32_bf16(qhi0, klo0, acc, 0, 0, 0);
      acc = __builtin_amdgcn_mfma_f32_16x16x32_bf16(qhi1, klo1, acc, 0, 0, 0);
      acc = __builtin_amdgcn_mfma_f32_16x16x32_bf16(qlo0, khi0, acc, 0, 0, 0);
      acc = __builtin_amdgcn_mfma_f32_16x16x32_bf16(qlo1, khi1, acc, 0, 0, 0);
      y2[t][0] = __builtin_shufflevector(acc, acc, 0, 1);
      y2[t][1] = __builtin_shufflevector(acc, acc, 2, 3);
    }
  }

  // ---- phase 2: row max; convert scores -> y0 = -(s + c0), c0 = -max-1 ----
  {
    f32x2 mx2[2] = {y2[0][0], y2[0][1]};
#pragma unroll
    for (int t = 1; t < TPW; ++t) {
#pragma unroll
      for (int j = 0; j < 2; ++j) {
        mx2[j].x = fmaxf(mx2[j].x, y2[t][j].x);
        mx2[j].y = fmaxf(mx2[j].y, y2[t][j].y);
      }
    }
#pragma unroll
    for (int j = 0; j < 2; ++j) {
      ROR_MAX(mx2[j].x, 8); ROR_MAX(mx2[j].x, 4); ROR_MAX(mx2[j].x, 2); ROR_MAX(mx2[j].x, 1);
      ROR_MAX(mx2[j].y, 8); ROR_MAX(mx2[j].y, 4); ROR_MAX(mx2[j].y, 2); ROR_MAX(mx2[j].y, 1);
    }
    if (l16 < 4) {
      float v = (l16 == 0) ? mx2[0].x : (l16 == 1) ? mx2[0].y
              : (l16 == 2) ? mx2[1].x : mx2[1].y;
      redmax[w][quad * 4 + l16] = v;
    }
    __syncthreads();
    f32x2 negc[2];
#pragma unroll
    for (int r = 0; r < 4; ++r) {
      float m = redmax[l16 & 7][quad * 4 + r];
      ROR_MAX(m, 4); ROR_MAX(m, 2); ROR_MAX(m, 1);
      ((float*)negc)[r] = m + 1.0f;            // -c0 = max + 1
    }
#pragma unroll
    for (int t = 0; t < TPW; ++t) {
#pragma unroll
      for (int j = 0; j < 2; ++j) y2[t][j] = negc[j] - y2[t][j];  // y = -s - c0
    }
  }

  // ---- phase 3: Newton x6 on y (y += step each iter); paired reciprocals ----
  for (int it = 0; it < NEWTON; ++it) {
    const int par = it & 1;
    f32x2 ps2[2] = {{0.f, 0.f}, {0.f, 0.f}};
    f32x2 psd2[2] = {{0.f, 0.f}, {0.f, 0.f}};
#pragma unroll
    for (int t = 0; t < TPW; ++t) {
#pragma unroll
      for (int j = 0; j < 2; ++j) {
        f32x2 y = y2[t][j];
        float z = __builtin_amdgcn_rcpf(y.x * y.y);
        f32x2 r1 = z * __builtin_shufflevector(y, y, 1, 0);  // (1/y.x, 1/y.y)
        f32x2 r2 = r1 * r1;
        ps2[j] += r2;
        psd2[j] += r2 * r1;
      }
    }
#pragma unroll
    for (int j = 0; j < 2; ++j) {
      ROR_ADD(ps2[j].x, 8);  ROR_ADD(ps2[j].x, 4);  ROR_ADD(ps2[j].x, 2);  ROR_ADD(ps2[j].x, 1);
      ROR_ADD(ps2[j].y, 8);  ROR_ADD(ps2[j].y, 4);  ROR_ADD(ps2[j].y, 2);  ROR_ADD(ps2[j].y, 1);
      ROR_ADD(psd2[j].x, 8); ROR_ADD(psd2[j].x, 4); ROR_ADD(psd2[j].x, 2); ROR_ADD(psd2[j].x, 1);
      ROR_ADD(psd2[j].y, 8); ROR_ADD(psd2[j].y, 4); ROR_ADD(psd2[j].y, 2); ROR_ADD(psd2[j].y, 1);
    }
    if (l16 < 4) {
      float a = (l16 == 0) ? ps2[0].x : (l16 == 1) ? ps2[0].y
              : (l16 == 2) ? ps2[1].x : ps2[1].y;
      float d = (l16 == 0) ? psd2[0].x : (l16 == 1) ? psd2[0].y
              : (l16 == 2) ? psd2[1].x : psd2[1].y;
      redq[par][w][quad * 4 + l16] = f32x2{a, d};
    }
    __syncthreads();
    f32x2 st[2];
#pragma unroll
    for (int r = 0; r < 4; ++r) {
      f32x2 v = redq[par][l16 & 7][quad * 4 + r];
      ROR_ADD(v.x, 4); ROR_ADD(v.x, 2); ROR_ADD(v.x, 1);
      ROR_ADD(v.y, 4); ROR_ADD(v.y, 2); ROR_ADD(v.y, 1);
      // c -= (ps-1)/(2 psd + eps)  =>  y += (ps-1)/(2 psd + eps)
      ((float*)st)[r] =
          (v.x - 1.0f) * __builtin_amdgcn_rcpf(2.0f * v.y + 1e-8f);
    }
#pragma unroll
    for (int t = 0; t < TPW; ++t) {
#pragma unroll
      for (int j = 0; j < 2; ++j) y2[t][j] += st[j];
    }
  }

  // ---- phase 5: weights = 1/y^2 on the fly; O_partial = W * (Vhi + Vlo) ----
  f32x4 oacc[4];
#pragma unroll
  for (int n = 0; n < 4; ++n) oacc[n] = (f32x4){0.f, 0.f, 0.f, 0.f};
  float* myslab = &ex[w][0][0];
  const __bf16* vpbh = vp_hi + (size_t)bh * 131072;
  const __bf16* vpbl = vp_lo + (size_t)bh * 131072;
#pragma unroll
  for (int p = 0; p < 8; ++p) {
#pragma unroll
    for (int ts = 0; ts < 2; ++ts) {
      const int t = 2 * p + ts;
#pragma unroll
      for (int j = 0; j < 2; ++j) {
        f32x2 y = y2[t][j];
        float z = __builtin_amdgcn_rcpf(y.x * y.y);
        f32x2 u = z * __builtin_shufflevector(y, y, 1, 0);
        f32x2 wgt = u * u;
        myslab[(quad * 4 + 2 * j) * 68 + ts * 16 + l16] = wgt.x;
        myslab[(quad * 4 + 2 * j + 1) * 68 + ts * 16 + l16] = wgt.y;
      }
    }
    asm volatile("s_waitcnt lgkmcnt(0)" ::: "memory");  // wave-internal exchange
    f32x4 w0 = *(const f32x4*)(myslab + l16 * 68 + quad * 8);
    f32x4 w1 = *(const f32x4*)(myslab + l16 * 68 + quad * 8 + 4);
    bf16x8 aw;
#pragma unroll
    for (int j = 0; j < 4; ++j) {
      aw[j] = (__bf16)w0[j];
      aw[4 + j] = (__bf16)w1[j];
    }
    const size_t vo = ((size_t)(p * 8 + w) * 4) * 512 + lane * 8;
#pragma unroll
    for (int n = 0; n < 4; ++n) {
      bf16x8 bhv = *(const bf16x8*)(vpbh + vo + n * 512);
      bf16x8 blv = *(const bf16x8*)(vpbl + vo + n * 512);
      oacc[n] = __builtin_amdgcn_mfma_f32_16x16x32_bf16(aw, bhv, oacc[n], 0, 0, 0);
      oacc[n] = __builtin_amdgcn_mfma_f32_16x16x32_bf16(aw, blv, oacc[n], 0, 0, 0);
    }
    asm volatile("s_waitcnt lgkmcnt(0)" ::: "memory");
  }

  // ---- phase 6: reduce partials across waves, write global ----
#pragma unroll
  for (int n = 0; n < 4; ++n)
#pragma unroll
    for (int r = 0; r < 4; ++r)
      ex[w][quad * 4 + r][n * 16 + l16] = oacc[n][r];
  __syncthreads();
  {
    const int row = 2 * w + (lane >> 5);
    const int d = lane & 31;
    float v0 = 0.f, v1 = 0.f;
#pragma unroll
    for (int i = 0; i < WV; ++i) {
      v0 += ex[i][row][d];
      v1 += ex[i][row][d + 32];
    }
    const int off = ((b * NL + qbase + row) * NH + h) * ND + d;
    outg[off] = v0;
    outg[off + 32] = v1;
  }
}

extern "C" void kernel_launch(void* const* d_in, const int* in_sizes, int n_in,
                              void* d_out, int out_size, void* d_ws, size_t ws_size,
                              hipStream_t stream) {
  const float* q = (const float*)d_in[0];
  const float* k = (const float*)d_in[1];
  const float* v = (const float*)d_in[2];

  const size_t plane = (size_t)NB * NH * ND * NL;  // 3.15M elems, 6.29MB/plane
  __bf16* kp_hi = (__bf16*)d_ws;
  __bf16* kp_lo = kp_hi + plane;
  __bf16* vp_hi = kp_lo + plane;
  __bf16* vp_lo = vp_hi + plane;

  prep<<<NB * 128 * 3, 256, 0, stream>>>(k, v, kp_hi, kp_lo, vp_hi, vp_lo);

  attn_poly<<<NB * NH * (NL / 16), 512, 0, stream>>>(
      q, kp_hi, kp_lo, vp_hi, vp_lo, (float*)d_out);
}